// Round 5
// baseline (20.915 us; speedup 1.0000x reference)
//
#include <hip/hip_runtime.h>

// SigNet forward, closed-form (scan-free) depth-3 signature + Linear,
// split into a 2-kernel pipeline for occupancy.
// B=256, L=256, CIN=8, C=9, SIG_CH=819, OUT=128.
//
// s1[i]       = x_L[i]
// s2[i][j]    = sum_l w_l[i] * d_l[j]                   w = x_{l-1} + 0.5*d
// s3[i][j][k] = s2[i][j]*x_L[k]
//             + sum_l ( z_l[i]*d_l[j]*d_l[k] - w_l[i]*d_l[j]*x_l[k] )
//   with z = 0.5*w - d/12,  x = w + 0.5*d   (only W,D tables needed in LDS)
//
// All sums use ABSOLUTE x -> they split over l. Kernel1: 2 blocks/batch,
// 128 segments each, partial s2[81]+s3'[729] -> ws. Kernel2: 2 blocks/batch
// (64 outputs each): combine halves, add s2 (x) x_L cross-term, Linear.

#define ROWF    132           // table row stride in floats (132%32==4)
#define NCHUNK  16
#define TPC     27
#define ASTRIDE 29
#define DUMPF   (NCHUNK * TPC * ASTRIDE)     // 12528 floats
#define U1SZ    (DUMPF + NCHUNK * 81)        // 13824 floats = 55.3 KB
#define WSSTR   812                          // ws row stride (16B aligned)

__global__ __launch_bounds__(512) void signet_part(
    const float* __restrict__ inp,   // [256, 256, 8]
    float* __restrict__ ws)          // [512][WSSTR]
{
    __shared__ __align__(16) float u[U1SZ];

    const int tid = threadIdx.x;
    const int blk = blockIdx.x;
    const int b   = blk >> 1;
    const int seg = blk & 1;          // l-columns [seg*128, seg*128+128)

    float* Wt = u;                    // [9][ROWF]
    float* Dt = u + 9 * ROWF;         // [9][ROWF]

    // ---- prep: local col -> global segment gt = seg*128+col ----
    {
        const int col = tid & 127;
        const int gt  = seg * 128 + col;
        const float* rc = inp + (size_t)b * 2048 + (size_t)gt * 8;
        if (tid < 128) {
            float4 c0 = *(const float4*)rc;
            float4 p0 = make_float4(0.f, 0.f, 0.f, 0.f);
            float  tp = 0.f;
            if (gt > 0) { p0 = *(const float4*)(rc - 8); tp = (float)(gt - 1) * (1.0f / 255.0f); }
            float cur[5] = { (float)gt * (1.0f / 255.0f), c0.x, c0.y, c0.z, c0.w };
            float prv[5] = { tp, p0.x, p0.y, p0.z, p0.w };
            #pragma unroll
            for (int c = 0; c < 5; ++c) {
                const float d = cur[c] - prv[c];
                Dt[c * ROWF + col] = d;
                Wt[c * ROWF + col] = prv[c] + 0.5f * d;
            }
        } else if (tid < 256) {
            float4 c1 = *(const float4*)(rc + 4);
            float4 p1 = make_float4(0.f, 0.f, 0.f, 0.f);
            if (gt > 0) p1 = *(const float4*)(rc - 4);
            float cur[4] = { c1.x, c1.y, c1.z, c1.w };
            float prv[4] = { p1.x, p1.y, p1.z, p1.w };
            #pragma unroll
            for (int c = 0; c < 4; ++c) {
                const float d = cur[c] - prv[c];
                Dt[(5 + c) * ROWF + col] = d;
                Wt[(5 + c) * ROWF + col] = prv[c] + 0.5f * d;
            }
        }
    }
    __syncthreads();

    // ---- main: chunk = tid/27 handles float4 cols {2*chunk, 2*chunk+1} ----
    const int  chunk = tid / TPC;            // 0..18 (>=16 idle)
    const int  tloc  = tid - chunk * TPC;    // 0..26
    const int  ci    = tloc / 3;             // channel i
    const int  kt    = tloc - ci * 3;        // k-triple
    const bool act   = (chunk < NCHUNK);

    float a[9][3];
    float s2a[9];
    #pragma unroll
    for (int j = 0; j < 9; ++j) { s2a[j] = 0.f; a[j][0] = 0.f; a[j][1] = 0.f; a[j][2] = 0.f; }

    if (act) {
        const float4* W4 = (const float4*)u;             // [9][33]
        const float4* D4 = (const float4*)u + 9 * 33;
        const int k0 = 3 * kt;
        const int fb = chunk * 2;

        #pragma unroll
        for (int q = 0; q < 2; ++q) {
            const int idx = fb + q;
            const float4 w   = W4[ci * 33 + idx];
            const float4 di  = D4[ci * 33 + idx];
            const float4 Wk0 = W4[(k0 + 0) * 33 + idx];
            const float4 Wk1 = W4[(k0 + 1) * 33 + idx];
            const float4 Wk2 = W4[(k0 + 2) * 33 + idx];
            const float4 Dk0 = D4[(k0 + 0) * 33 + idx];
            const float4 Dk1 = D4[(k0 + 1) * 33 + idx];
            const float4 Dk2 = D4[(k0 + 2) * 33 + idx];

            float4 z, X0, X1, X2;
            z.x = fmaf(-(1.0f / 12.0f), di.x, 0.5f * w.x);
            z.y = fmaf(-(1.0f / 12.0f), di.y, 0.5f * w.y);
            z.z = fmaf(-(1.0f / 12.0f), di.z, 0.5f * w.z);
            z.w = fmaf(-(1.0f / 12.0f), di.w, 0.5f * w.w);
            X0.x = fmaf(0.5f, Dk0.x, Wk0.x); X0.y = fmaf(0.5f, Dk0.y, Wk0.y);
            X0.z = fmaf(0.5f, Dk0.z, Wk0.z); X0.w = fmaf(0.5f, Dk0.w, Wk0.w);
            X1.x = fmaf(0.5f, Dk1.x, Wk1.x); X1.y = fmaf(0.5f, Dk1.y, Wk1.y);
            X1.z = fmaf(0.5f, Dk1.z, Wk1.z); X1.w = fmaf(0.5f, Dk1.w, Wk1.w);
            X2.x = fmaf(0.5f, Dk2.x, Wk2.x); X2.y = fmaf(0.5f, Dk2.y, Wk2.y);
            X2.z = fmaf(0.5f, Dk2.z, Wk2.z); X2.w = fmaf(0.5f, Dk2.w, Wk2.w);

            #pragma unroll
            for (int j = 0; j < 9; ++j) {
                const float4 dj = D4[j * 33 + idx];
                { const float uu = w.x * dj.x, vv = z.x * dj.x; s2a[j] += uu;
                  a[j][0] = fmaf(vv, Dk0.x, fmaf(-uu, X0.x, a[j][0]));
                  a[j][1] = fmaf(vv, Dk1.x, fmaf(-uu, X1.x, a[j][1]));
                  a[j][2] = fmaf(vv, Dk2.x, fmaf(-uu, X2.x, a[j][2])); }
                { const float uu = w.y * dj.y, vv = z.y * dj.y; s2a[j] += uu;
                  a[j][0] = fmaf(vv, Dk0.y, fmaf(-uu, X0.y, a[j][0]));
                  a[j][1] = fmaf(vv, Dk1.y, fmaf(-uu, X1.y, a[j][1]));
                  a[j][2] = fmaf(vv, Dk2.y, fmaf(-uu, X2.y, a[j][2])); }
                { const float uu = w.z * dj.z, vv = z.z * dj.z; s2a[j] += uu;
                  a[j][0] = fmaf(vv, Dk0.z, fmaf(-uu, X0.z, a[j][0]));
                  a[j][1] = fmaf(vv, Dk1.z, fmaf(-uu, X1.z, a[j][1]));
                  a[j][2] = fmaf(vv, Dk2.z, fmaf(-uu, X2.z, a[j][2])); }
                { const float uu = w.w * dj.w, vv = z.w * dj.w; s2a[j] += uu;
                  a[j][0] = fmaf(vv, Dk0.w, fmaf(-uu, X0.w, a[j][0]));
                  a[j][1] = fmaf(vv, Dk1.w, fmaf(-uu, X1.w, a[j][1]));
                  a[j][2] = fmaf(vv, Dk2.w, fmaf(-uu, X2.w, a[j][2])); }
            }
        }
    }
    __syncthreads();          // all table reads done -> dump may alias tables

    if (act) {
        float* pa = u + tid * ASTRIDE;
        #pragma unroll
        for (int j = 0; j < 9; ++j) {
            pa[j * 3 + 0] = a[j][0];
            pa[j * 3 + 1] = a[j][1];
            pa[j * 3 + 2] = a[j][2];
        }
        if (kt == 0) {
            float* ps = u + DUMPF + chunk * 81 + ci * 9;
            #pragma unroll
            for (int j = 0; j < 9; ++j) ps[j] = s2a[j];
        }
    }
    __syncthreads();

    // ---- combine chunk partials, write block partial to ws ----
    float* wrow = ws + (size_t)blk * WSSTR;
    if (tid < 81) {
        float s = 0.f;
        #pragma unroll
        for (int c = 0; c < NCHUNK; ++c) s += u[DUMPF + c * 81 + tid];
        wrow[tid] = s;
    }
    for (int e = tid; e < 729; e += 512) {
        const int i   = e / 81;
        const int r   = e - i * 81;
        const int j   = r / 9;
        const int k   = r - j * 9;
        const int ktv = k / 3;
        const int km  = k - ktv * 3;
        const int toff = (i * 3 + ktv) * ASTRIDE + j * 3 + km;
        float s = 0.f;
        #pragma unroll
        for (int c = 0; c < NCHUNK; ++c) s += u[c * (TPC * ASTRIDE) + toff];
        wrow[81 + e] = s;
    }
}

__global__ __launch_bounds__(512) void signet_fin(
    const float* __restrict__ inp,   // [256, 256, 8]
    const float* __restrict__ ws,    // [512][WSSTR]
    const float* __restrict__ Wg,    // [819, 128]
    const float* __restrict__ bias,  // [128]
    float* __restrict__ out)         // [256, 128]
{
    __shared__ float sig[820];
    __shared__ __align__(16) float4 pbuf[32][16];

    const int tid = threadIdx.x;
    const int b   = blockIdx.x >> 1;
    const int h   = blockIdx.x & 1;       // output half: cols [h*64, h*64+64)

    const float* pa = ws + (size_t)(2 * b) * WSSTR;
    const float* pb = pa + WSSTR;

    if (tid < 81) sig[9 + tid] = pa[tid] + pb[tid];
    if (tid < 9)  sig[tid] = (tid == 0) ? 1.0f
                             : inp[(size_t)b * 2048 + 255 * 8 + (tid - 1)];
    __syncthreads();

    for (int e = tid; e < 729; e += 512) {
        const int i = e / 81;
        const int r = e - i * 81;
        const int j = r / 9;
        const int k = r - j * 9;
        sig[90 + e] = pa[81 + e] + pb[81 + e] + sig[9 + i * 9 + j] * sig[k];
    }
    __syncthreads();

    // ---- linear over output half h ----
    {
        const int oq = tid & 15;     // float4 within half
        const int sl = tid >> 4;     // channel slice 0..31
        const int cb = h * 16 + oq;  // float4 col in full row
        float4 acc = make_float4(0.f, 0.f, 0.f, 0.f);
        const float4* Wq = (const float4*)Wg;
        for (int ch = sl; ch < 819; ch += 32) {
            const float s = sig[ch];
            const float4 wv = Wq[(size_t)ch * 32 + cb];
            acc.x = fmaf(s, wv.x, acc.x);
            acc.y = fmaf(s, wv.y, acc.y);
            acc.z = fmaf(s, wv.z, acc.z);
            acc.w = fmaf(s, wv.w, acc.w);
        }
        pbuf[sl][oq] = acc;
    }
    __syncthreads();
    if (tid < 16) {
        float4 r = pbuf[0][tid];
        #pragma unroll
        for (int s = 1; s < 32; ++s) {
            const float4 p = pbuf[s][tid];
            r.x += p.x; r.y += p.y; r.z += p.z; r.w += p.w;
        }
        const float4 bv = ((const float4*)bias)[h * 16 + tid];
        r.x += bv.x; r.y += bv.y; r.z += bv.z; r.w += bv.w;
        ((float4*)(out + (size_t)b * 128 + h * 64))[tid] = r;
    }
}

extern "C" void kernel_launch(void* const* d_in, const int* in_sizes, int n_in,
                              void* d_out, int out_size, void* d_ws, size_t ws_size,
                              hipStream_t stream) {
    const float* inp  = (const float*)d_in[0];
    const float* Wp   = (const float*)d_in[1];
    const float* bias = (const float*)d_in[2];
    float* outp = (float*)d_out;
    float* wsp  = (float*)d_ws;
    (void)in_sizes; (void)n_in; (void)out_size; (void)ws_size;

    hipLaunchKernelGGL(signet_part, dim3(512), dim3(512), 0, stream, inp, wsp);
    hipLaunchKernelGGL(signet_fin,  dim3(512), dim3(512), 0, stream,
                       inp, wsp, Wp, bias, outp);
}